// Round 1
// baseline (99.932 us; speedup 1.0000x reference)
//
#include <hip/hip_runtime.h>
#include <stdint.h>

// ContrastiveLoss: B=8192, D=1024, n=2048, T=0.5
// K1: row-normalize f32 -> bf16 (ws)
// K2: fused MFMA GEMM S = 2*z[:2048] @ z^T with exp-row-sum (denom) + triu sum
// K3: scalar finalize

#define BDIM 1024
#define BROWS 8192
#define NROWS 2048

typedef __attribute__((ext_vector_type(8))) short bf16x8;
typedef __attribute__((ext_vector_type(4))) float f32x4;

static __device__ __forceinline__ unsigned short f2bf(float x) {
  union { float f; unsigned int u; } a; a.f = x;
  unsigned int u = a.u;
  return (unsigned short)((u + 0x7fffu + ((u >> 16) & 1u)) >> 16);  // RNE
}

__global__ __launch_bounds__(256) void normalize_kernel(const float* __restrict__ emb,
                                                        unsigned short* __restrict__ zb) {
  const int row = blockIdx.x;
  const int t = threadIdx.x;
  const float4 v = reinterpret_cast<const float4*>(emb + (size_t)row * BDIM)[t];
  float ss = v.x * v.x + v.y * v.y + v.z * v.z + v.w * v.w;
#pragma unroll
  for (int m = 1; m < 64; m <<= 1) ss += __shfl_xor(ss, m);
  __shared__ float wsum[4];
  if ((t & 63) == 0) wsum[t >> 6] = ss;
  __syncthreads();
  const float inv = rsqrtf(wsum[0] + wsum[1] + wsum[2] + wsum[3]);
  ushort4 o;
  o.x = f2bf(v.x * inv);
  o.y = f2bf(v.y * inv);
  o.z = f2bf(v.z * inv);
  o.w = f2bf(v.w * inv);
  reinterpret_cast<ushort4*>(zb + (size_t)row * BDIM)[t] = o;
}

// 128x128 tile, BK=32, 4 waves (each wave: 64x64 = 4x4 frags of 16x16x32 bf16 MFMA)
#define BM 128
#define BN 128
#define BK 32

__global__ __launch_bounds__(256) void gemm_fused(const unsigned short* __restrict__ zb,
                                                  float* __restrict__ denom,
                                                  float* __restrict__ sumsim) {
  __shared__ unsigned short As[BM * BK];
  __shared__ unsigned short Bs[BN * BK];
  const int i0 = blockIdx.y * BM;  // [0, 2048)
  const int j0 = blockIdx.x * BN;  // [0, 8192)
  const int t = threadIdx.x;
  const int lane = t & 63;
  const int w = t >> 6;
  const int wr = w >> 1, wc = w & 1;

  f32x4 acc[4][4] = {};

  const int srow = t >> 2;     // 0..63
  const int schunk = t & 3;    // 16B chunk within a 64B row

  for (int k0 = 0; k0 < BDIM; k0 += BK) {
    __syncthreads();  // previous iter's reads done before overwrite
    {
      const int r0 = srow, r1 = srow + 64;
      const uint4 a0 = *reinterpret_cast<const uint4*>(zb + (size_t)(i0 + r0) * BDIM + k0 + schunk * 8);
      const uint4 a1 = *reinterpret_cast<const uint4*>(zb + (size_t)(i0 + r1) * BDIM + k0 + schunk * 8);
      const uint4 b0 = *reinterpret_cast<const uint4*>(zb + (size_t)(j0 + r0) * BDIM + k0 + schunk * 8);
      const uint4 b1 = *reinterpret_cast<const uint4*>(zb + (size_t)(j0 + r1) * BDIM + k0 + schunk * 8);
      // XOR-swizzled 16B slot to break ds_read_b128 bank conflicts
      *reinterpret_cast<uint4*>(&As[r0 * BK + ((schunk ^ (r0 & 3)) * 8)]) = a0;
      *reinterpret_cast<uint4*>(&As[r1 * BK + ((schunk ^ (r1 & 3)) * 8)]) = a1;
      *reinterpret_cast<uint4*>(&Bs[r0 * BK + ((schunk ^ (r0 & 3)) * 8)]) = b0;
      *reinterpret_cast<uint4*>(&Bs[r1 * BK + ((schunk ^ (r1 & 3)) * 8)]) = b1;
    }
    __syncthreads();

    bf16x8 af[4], bfr[4];
    const int q = lane >> 4;
    const int rsub = lane & 15;
#pragma unroll
    for (int m = 0; m < 4; m++) {
      const int r = wr * 64 + m * 16 + rsub;
      af[m] = *reinterpret_cast<const bf16x8*>(&As[r * BK + ((q ^ (r & 3)) * 8)]);
    }
#pragma unroll
    for (int n = 0; n < 4; n++) {
      const int r = wc * 64 + n * 16 + rsub;
      bfr[n] = *reinterpret_cast<const bf16x8*>(&Bs[r * BK + ((q ^ (r & 3)) * 8)]);
    }
#pragma unroll
    for (int m = 0; m < 4; m++)
#pragma unroll
      for (int n = 0; n < 4; n++)
        acc[m][n] = __builtin_amdgcn_mfma_f32_16x16x32_bf16(af[m], bfr[n], acc[m][n], 0, 0, 0);
  }

  // Epilogue: S = 2*acc. C/D layout: col = lane&15, row = (lane>>4)*4 + reg.
  const int hi = lane >> 4;
  const int col_l = lane & 15;
  float ssim = 0.f;
#pragma unroll
  for (int m = 0; m < 4; m++) {
    const int gibase = i0 + wr * 64 + m * 16 + hi * 4;
#pragma unroll
    for (int r = 0; r < 4; r++) {
      const int gi = gibase + r;
      float dsum = 0.f;
#pragma unroll
      for (int n = 0; n < 4; n++) {
        const int gj = j0 + wc * 64 + n * 16 + col_l;
        const float s = acc[m][n][r] * 2.0f;
        const float e = __expf(s);
        if (gj != gi) dsum += e;          // exclude diagonal from denom
        if (gj < NROWS && gi < gj) ssim += s;  // triu(rows[:, :n], k=1)
      }
      dsum += __shfl_xor(dsum, 1);
      dsum += __shfl_xor(dsum, 2);
      dsum += __shfl_xor(dsum, 4);
      dsum += __shfl_xor(dsum, 8);
      if (col_l == 0) atomicAdd(&denom[gi], dsum);
    }
  }
#pragma unroll
  for (int msk = 1; msk < 64; msk <<= 1) ssim += __shfl_xor(ssim, msk);
  if (lane == 0 && j0 < NROWS) atomicAdd(sumsim, ssim);
}

__global__ __launch_bounds__(256) void finalize(const float* __restrict__ denom,
                                                const float* __restrict__ sumsim,
                                                float* __restrict__ out) {
  const int t = threadIdx.x;
  double s = 0.0;
  for (int i = t; i < NROWS; i += 256) {
    s += (double)(NROWS - 1 - i) * log((double)denom[i]);
  }
#pragma unroll
  for (int m = 1; m < 64; m <<= 1) s += __shfl_xor(s, m);
  __shared__ double ws_[4];
  if ((t & 63) == 0) ws_[t >> 6] = s;
  __syncthreads();
  if (t == 0) {
    const double loss = (ws_[0] + ws_[1] + ws_[2] + ws_[3]) - (double)sumsim[0];
    out[0] = (float)(-2.0 / (double)NROWS * (double)(NROWS - 1) * loss);
  }
}

extern "C" void kernel_launch(void* const* d_in, const int* in_sizes, int n_in,
                              void* d_out, int out_size, void* d_ws, size_t ws_size,
                              hipStream_t stream) {
  const float* emb = (const float*)d_in[0];
  unsigned short* zb = (unsigned short*)d_ws;
  float* denom = (float*)((char*)d_ws + (size_t)BROWS * BDIM * 2);
  float* sumsim = denom + NROWS;
  float* out = (float*)d_out;

  hipMemsetAsync(denom, 0, (NROWS + 1) * sizeof(float), stream);
  normalize_kernel<<<BROWS, 256, 0, stream>>>(emb, zb);
  gemm_fused<<<dim3(BROWS / BN, NROWS / BM), 256, 0, stream>>>(zb, denom, sumsim);
  finalize<<<1, 256, 0, stream>>>(denom, sumsim, out);
}

// Round 2
// 91.903 us; speedup vs baseline: 1.0874x; 1.0874x over previous
//
#include <hip/hip_runtime.h>
#include <stdint.h>

// ContrastiveLoss: B=8192, D=1024, n=2048, T=0.5
// K1: row-normalize f32 -> bf16 (one wave per row), zero denom/sumsim
// K2: fused MFMA GEMM S = 2*z[:2048] @ z^T, global_load_lds + 2-phase dbuf,
//     epilogue: exp-row-sum (denom, diag excluded) + triu sum
// K3: scalar finalize

#define BDIM 1024
#define BROWS 8192
#define NROWS 2048

typedef __attribute__((ext_vector_type(8))) short bf16x8;
typedef __attribute__((ext_vector_type(4))) float f32x4;

static __device__ __forceinline__ unsigned short f2bf(float x) {
  union { float f; unsigned int u; } a; a.f = x;
  unsigned int u = a.u;
  return (unsigned short)((u + 0x7fffu + ((u >> 16) & 1u)) >> 16);  // RNE
}

// async 16B/lane global->LDS (lds dest: wave-uniform base + lane*16)
static __device__ __forceinline__ void gload_lds16(const unsigned short* g, unsigned short* l) {
  __builtin_amdgcn_global_load_lds(
      (const __attribute__((address_space(1))) uint32_t*)(const void*)g,
      (__attribute__((address_space(3))) uint32_t*)(void*)l,
      16, 0, 0);
}

__global__ __launch_bounds__(256) void normalize_kernel(const float* __restrict__ emb,
                                                        unsigned short* __restrict__ zb,
                                                        float* __restrict__ denom,
                                                        float* __restrict__ sumsim) {
  const int w = threadIdx.x >> 6;
  const int lane = threadIdx.x & 63;
  const int row = blockIdx.x * 4 + w;
  const float4* src = reinterpret_cast<const float4*>(emb + (size_t)row * BDIM);
  float4 v[4];
  float ss = 0.f;
#pragma unroll
  for (int i = 0; i < 4; i++) {
    v[i] = src[lane + i * 64];
    ss += v[i].x * v[i].x + v[i].y * v[i].y + v[i].z * v[i].z + v[i].w * v[i].w;
  }
#pragma unroll
  for (int m = 1; m < 64; m <<= 1) ss += __shfl_xor(ss, m);
  const float inv = rsqrtf(ss);
  ushort4* dst = reinterpret_cast<ushort4*>(zb + (size_t)row * BDIM);
#pragma unroll
  for (int i = 0; i < 4; i++) {
    ushort4 o;
    o.x = f2bf(v[i].x * inv);
    o.y = f2bf(v[i].y * inv);
    o.z = f2bf(v[i].z * inv);
    o.w = f2bf(v[i].w * inv);
    dst[lane + i * 64] = o;
  }
  if (blockIdx.x < NROWS / 4 && lane == 0) denom[row] = 0.f;  // rows 0..2047
  if (blockIdx.x == 0 && threadIdx.x == 0) sumsim[0] = 0.f;
}

// 128x128 tile, BK=32, 4 waves (each wave: 64x64 = 4x4 frags of 16x16x32 bf16 MFMA)
#define BM 128
#define BN 128
#define BK 32
#define NKT (BDIM / BK)

__global__ __launch_bounds__(256) void gemm_fused(const unsigned short* __restrict__ zb,
                                                  float* __restrict__ denom,
                                                  float* __restrict__ sumsim) {
  __shared__ unsigned short As[2][BM * BK];
  __shared__ unsigned short Bs[2][BN * BK];
  const int i0 = blockIdx.y * BM;  // [0, 2048)
  const int j0 = blockIdx.x * BN;  // [0, 8192)
  const int t = threadIdx.x;
  const int lane = t & 63;
  const int w = t >> 6;
  const int wr = w >> 1, wc = w & 1;

  f32x4 acc[4][4] = {};

  // staging: wave w covers rows [w*32, w*32+32), 2 loads x 16 rows, for A and B.
  // lane -> rloc = lane>>2, slot = lane&3; fetch global chunk c = slot ^ ((r>>1)&3)
  // so that LDS slot s of row r holds chunk s ^ ((r>>1)&3) (2-way-free read swizzle).
  const int rloc = lane >> 2;
  const int slot = lane & 3;

#define STAGE(buf, k0)                                                              \
  {                                                                                 \
    _Pragma("unroll") for (int p = 0; p < 2; ++p) {                                 \
      const int r = w * 32 + p * 16 + rloc;                                         \
      const int c = slot ^ ((r >> 1) & 3);                                          \
      gload_lds16(zb + (size_t)(i0 + r) * BDIM + (k0) + c * 8,                      \
                  &As[buf][(w * 32 + p * 16) * BK]);                                \
      gload_lds16(zb + (size_t)(j0 + r) * BDIM + (k0) + c * 8,                      \
                  &Bs[buf][(w * 32 + p * 16) * BK]);                                \
    }                                                                               \
  }

  STAGE(0, 0);
  __syncthreads();  // vmcnt(0) drained by compiler before s_barrier

  const int q = lane >> 4;      // k-chunk wanted
  const int rsub = lane & 15;

  int cur = 0;
  for (int kt = 0; kt < NKT; ++kt) {
    if (kt + 1 < NKT) STAGE(cur ^ 1, (kt + 1) * BK);

    bf16x8 af[4], bfr[4];
#pragma unroll
    for (int m = 0; m < 4; m++) {
      const int r = wr * 64 + m * 16 + rsub;
      const int s = q ^ ((r >> 1) & 3);
      af[m] = *reinterpret_cast<const bf16x8*>(&As[cur][r * BK + s * 8]);
    }
#pragma unroll
    for (int n = 0; n < 4; n++) {
      const int r = wc * 64 + n * 16 + rsub;
      const int s = q ^ ((r >> 1) & 3);
      bfr[n] = *reinterpret_cast<const bf16x8*>(&Bs[cur][r * BK + s * 8]);
    }
#pragma unroll
    for (int m = 0; m < 4; m++)
#pragma unroll
      for (int n = 0; n < 4; n++)
        acc[m][n] = __builtin_amdgcn_mfma_f32_16x16x32_bf16(af[m], bfr[n], acc[m][n], 0, 0, 0);

    __syncthreads();  // waits lgkm (ds reads) + vm (prefetch landed)
    cur ^= 1;
  }

  // Epilogue: S = 2*acc. C/D layout: col = lane&15, row = (lane>>4)*4 + reg.
  const int hi = lane >> 4;
  const int col_l = lane & 15;
  float ssim = 0.f;
#pragma unroll
  for (int m = 0; m < 4; m++) {
    const int gibase = i0 + wr * 64 + m * 16 + hi * 4;
#pragma unroll
    for (int r = 0; r < 4; r++) {
      const int gi = gibase + r;
      float dsum = 0.f;
#pragma unroll
      for (int n = 0; n < 4; n++) {
        const int gj = j0 + wc * 64 + n * 16 + col_l;
        const float s = acc[m][n][r] * 2.0f;
        const float e = __expf(s);
        if (gj != gi) dsum += e;               // exclude diagonal from denom
        if (gj < NROWS && gi < gj) ssim += s;  // triu(rows[:, :n], k=1)
      }
      dsum += __shfl_xor(dsum, 1);
      dsum += __shfl_xor(dsum, 2);
      dsum += __shfl_xor(dsum, 4);
      dsum += __shfl_xor(dsum, 8);
      if (col_l == 0) atomicAdd(&denom[gi], dsum);
    }
  }
#pragma unroll
  for (int msk = 1; msk < 64; msk <<= 1) ssim += __shfl_xor(ssim, msk);
  if (lane == 0 && j0 < NROWS) atomicAdd(sumsim, ssim);
}

__global__ __launch_bounds__(256) void finalize(const float* __restrict__ denom,
                                                const float* __restrict__ sumsim,
                                                float* __restrict__ out) {
  const int t = threadIdx.x;
  double s = 0.0;
  for (int i = t; i < NROWS; i += 256) {
    s += (double)(NROWS - 1 - i) * log((double)denom[i]);
  }
#pragma unroll
  for (int m = 1; m < 64; m <<= 1) s += __shfl_xor(s, m);
  __shared__ double ws_[4];
  if ((t & 63) == 0) ws_[t >> 6] = s;
  __syncthreads();
  if (t == 0) {
    const double loss = (ws_[0] + ws_[1] + ws_[2] + ws_[3]) - (double)sumsim[0];
    out[0] = (float)(-2.0 / (double)NROWS * (double)(NROWS - 1) * loss);
  }
}

extern "C" void kernel_launch(void* const* d_in, const int* in_sizes, int n_in,
                              void* d_out, int out_size, void* d_ws, size_t ws_size,
                              hipStream_t stream) {
  const float* emb = (const float*)d_in[0];
  unsigned short* zb = (unsigned short*)d_ws;
  float* denom = (float*)((char*)d_ws + (size_t)BROWS * BDIM * 2);
  float* sumsim = denom + NROWS;
  float* out = (float*)d_out;

  normalize_kernel<<<BROWS / 4, 256, 0, stream>>>(emb, zb, denom, sumsim);
  gemm_fused<<<dim3(BROWS / BN, NROWS / BM), 256, 0, stream>>>(zb, denom, sumsim);
  finalize<<<1, 256, 0, stream>>>(denom, sumsim, out);
}

// Round 3
// 71.810 us; speedup vs baseline: 1.3916x; 1.2798x over previous
//
#include <hip/hip_runtime.h>
#include <stdint.h>

// ContrastiveLoss: B=8192, D=1024, n=2048, T=0.5
// K1: row-normalize f32 -> bf16 (one wave per row), zero denom/sumsim
// K2: 256x256-tile MFMA GEMM (BK=64, 8 waves), 4-phase counted-vmcnt pipeline,
//     XCD-chunked block mapping; epilogue: exp-row-sum + triu sum
// K3: scalar finalize

#define BDIM 1024
#define BROWS 8192
#define NROWS 2048

#define BM 256
#define BN 256
#define BK 64
#define NKT (BDIM / BK)   // 16

typedef __attribute__((ext_vector_type(8))) short bf16x8;
typedef __attribute__((ext_vector_type(4))) float f32x4;

static __device__ __forceinline__ unsigned short f2bf(float x) {
  union { float f; unsigned int u; } a; a.f = x;
  unsigned int u = a.u;
  return (unsigned short)((u + 0x7fffu + ((u >> 16) & 1u)) >> 16);  // RNE
}

static __device__ __forceinline__ void gload_lds16(const unsigned short* g, unsigned short* l) {
  __builtin_amdgcn_global_load_lds(
      (const __attribute__((address_space(1))) uint32_t*)(const void*)g,
      (__attribute__((address_space(3))) uint32_t*)(void*)l,
      16, 0, 0);
}

__global__ __launch_bounds__(256) void normalize_kernel(const float* __restrict__ emb,
                                                        unsigned short* __restrict__ zb,
                                                        float* __restrict__ denom,
                                                        float* __restrict__ sumsim) {
  const int w = threadIdx.x >> 6;
  const int lane = threadIdx.x & 63;
  const int row = blockIdx.x * 4 + w;
  const float4* src = reinterpret_cast<const float4*>(emb + (size_t)row * BDIM);
  float4 v[4];
  float ss = 0.f;
#pragma unroll
  for (int i = 0; i < 4; i++) {
    v[i] = src[lane + i * 64];
    ss += v[i].x * v[i].x + v[i].y * v[i].y + v[i].z * v[i].z + v[i].w * v[i].w;
  }
#pragma unroll
  for (int m = 1; m < 64; m <<= 1) ss += __shfl_xor(ss, m);
  const float inv = rsqrtf(ss);
  ushort4* dst = reinterpret_cast<ushort4*>(zb + (size_t)row * BDIM);
#pragma unroll
  for (int i = 0; i < 4; i++) {
    ushort4 o;
    o.x = f2bf(v[i].x * inv);
    o.y = f2bf(v[i].y * inv);
    o.z = f2bf(v[i].z * inv);
    o.w = f2bf(v[i].w * inv);
    dst[lane + i * 64] = o;
  }
  if (blockIdx.x < NROWS / 4 && lane == 0) denom[row] = 0.f;
  if (blockIdx.x == 0 && threadIdx.x == 0) sumsim[0] = 0.f;
}

// ---------------- GEMM ----------------
// LDS: 2 buffers x (A 256x64 + B 256x64) bf16 = 128 KB.
// Row = 64 bf16 = 128 B = 8x16B slots. Read/store swizzle: logical slot s of row r
// lives at position s ^ (r&7)  (2-way-free ds_read_b128).
// Stage units per K-tile (2 gload_lds/thread each), first-need order:
//   U0 = A rows {0-63,128-191} (qm=0 quarters), U1 = B qn=0 strips,
//   U3 = B qn=1 strips, U2 = A rows {64-127,192-255}.
// Gates: vmcnt(4) at ph0 (covers U3), ph1 (U2), ph3 (U0,U1 of next tile). Never 0 in loop.

__global__ __launch_bounds__(512, 2) void gemm_fused(const unsigned short* __restrict__ zb,
                                                     float* __restrict__ denom,
                                                     float* __restrict__ sumsim) {
  __shared__ unsigned short As[2][BM * BK];
  __shared__ unsigned short Bs[2][BN * BK];

  // XCD-chunked mapping: xcd owns 4 j-blocks x all 8 i-blocks
  const int bx = blockIdx.x;           // 0..255
  const int xcd = bx & 7;
  const int idx = bx >> 3;             // 0..31
  const int jb = xcd * 4 + (idx & 3);  // 0..31
  const int ib = idx >> 2;             // 0..7
  const int i0 = ib * BM;              // [0,2048)
  const int j0 = jb * BN;              // [0,8192)

  const int t = threadIdx.x;
  const int lane = t & 63;
  const int w = t >> 6;                // 0..7
  const int WR = w >> 2;               // 0..1
  const int WC = w & 3;                // 0..3

  // staging constants
  const int rsh = lane >> 3;                 // 0..7 row within 8-row group
  const int slsrc = (lane & 7) ^ rsh;        // logical slot fetched for stored position lane&7
  // A-unit lds row bases (multiples of 8)
  const int a_u0 = w * 8;                    // rows 0-63
  const int b_u1 = (w >> 2) * 64 + (w & 3) * 8;  // U1 call0 base

  // read constants
  const int q = lane >> 4;       // 0..3
  const int rsub = lane & 15;
  const int rx7 = rsub & 7;
  const int sA0 = q ^ rx7;       // stored slot for kk=0 (kk=1 -> ^4)
  const int arow = WR * 128 + rsub;
  const int brow = WC * 64 + rsub;

  f32x4 acc[8][4] = {};
  bf16x8 aA[4][2], bf0[2][2], bf1[2][2];

#define STG_A(buf, lr0, kk0) \
  gload_lds16(zb + (size_t)(i0 + (lr0) + rsh) * BDIM + (kk0) + slsrc * 8, &As[buf][(lr0) * BK])
#define STG_B(buf, lr0, kk0) \
  gload_lds16(zb + (size_t)(j0 + (lr0) + rsh) * BDIM + (kk0) + slsrc * 8, &Bs[buf][(lr0) * BK])

#define LDA(buf, qm, mm, kk) \
  (*reinterpret_cast<const bf16x8*>(&As[buf][(size_t)(arow + (qm) * 64 + (mm) * 16) * BK + ((sA0 ^ ((kk)*4)) * 8)]))
#define LDB(buf, qn, nn, kk) \
  (*reinterpret_cast<const bf16x8*>(&Bs[buf][(size_t)(brow + (qn) * 32 + (nn) * 16) * BK + ((sA0 ^ ((kk)*4)) * 8)]))

#define MFMA_Q(MB, NB, BF)                                                                       \
  _Pragma("unroll") for (int mm = 0; mm < 4; mm++)                                               \
  _Pragma("unroll") for (int nn = 0; nn < 2; nn++) {                                             \
    acc[(MB) + mm][(NB) + nn] =                                                                  \
        __builtin_amdgcn_mfma_f32_16x16x32_bf16(aA[mm][0], BF[nn][0], acc[(MB) + mm][(NB) + nn], 0, 0, 0); \
    acc[(MB) + mm][(NB) + nn] =                                                                  \
        __builtin_amdgcn_mfma_f32_16x16x32_bf16(aA[mm][1], BF[nn][1], acc[(MB) + mm][(NB) + nn], 0, 0, 0); \
  }

#define BAR() __builtin_amdgcn_s_barrier()
#define WAIT_LGKM0()                                        \
  asm volatile("s_waitcnt lgkmcnt(0)" ::: "memory");        \
  __builtin_amdgcn_sched_barrier(0)

  // ---- prologue: stage tile 0 into buf 0 ----
  STG_A(0, a_u0, 0);        STG_A(0, 128 + a_u0, 0);        // U0
  STG_B(0, b_u1, 0);        STG_B(0, b_u1 + 128, 0);        // U1
  STG_B(0, b_u1 + 32, 0);   STG_B(0, b_u1 + 160, 0);        // U3
  STG_A(0, 64 + a_u0, 0);   STG_A(0, 192 + a_u0, 0);        // U2
  asm volatile("s_waitcnt vmcnt(0)" ::: "memory");
  BAR();

  int cur = 0;

#define K_TILE(PF, kn)                                                     \
  {                                                                        \
    const int nb = cur ^ 1;                                                \
    /* ---- ph0: (qm0,qn0); stage U0(next) ---- */                         \
    _Pragma("unroll") for (int mm = 0; mm < 4; mm++) {                     \
      aA[mm][0] = LDA(cur, 0, mm, 0); aA[mm][1] = LDA(cur, 0, mm, 1);      \
    }                                                                      \
    _Pragma("unroll") for (int nn = 0; nn < 2; nn++) {                     \
      bf0[nn][0] = LDB(cur, 0, nn, 0); bf0[nn][1] = LDB(cur, 0, nn, 1);    \
    }                                                                      \
    if (PF) { STG_A(nb, a_u0, kn); STG_A(nb, 128 + a_u0, kn); }            \
    if (PF) { asm volatile("s_waitcnt vmcnt(4)" ::: "memory"); }           \
    else    { asm volatile("s_waitcnt vmcnt(2)" ::: "memory"); }           \
    BAR();                                                                 \
    WAIT_LGKM0();                                                          \
    __builtin_amdgcn_s_setprio(1);                                         \
    MFMA_Q(0, 0, bf0);                                                     \
    __builtin_amdgcn_s_setprio(0);                                         \
    __builtin_amdgcn_sched_barrier(0);                                     \
    BAR();                                                                 \
    /* ---- ph1: (qm0,qn1); stage U1(next) ---- */                         \
    _Pragma("unroll") for (int nn = 0; nn < 2; nn++) {                     \
      bf1[nn][0] = LDB(cur, 1, nn, 0); bf1[nn][1] = LDB(cur, 1, nn, 1);    \
    }                                                                      \
    if (PF) { STG_B(nb, b_u1, kn); STG_B(nb, b_u1 + 128, kn); }            \
    if (PF) { asm volatile("s_waitcnt vmcnt(4)" ::: "memory"); }           \
    else    { asm volatile("s_waitcnt vmcnt(0)" ::: "memory"); }           \
    BAR();                                                                 \
    WAIT_LGKM0();                                                          \
    __builtin_amdgcn_s_setprio(1);                                         \
    MFMA_Q(0, 2, bf1);                                                     \
    __builtin_amdgcn_s_setprio(0);                                         \
    __builtin_amdgcn_sched_barrier(0);                                     \
    BAR();                                                                 \
    /* ---- ph2: (qm1,qn1); reload aA; stage U3(next); no gate ---- */     \
    _Pragma("unroll") for (int mm = 0; mm < 4; mm++) {                     \
      aA[mm][0] = LDA(cur, 1, mm, 0); aA[mm][1] = LDA(cur, 1, mm, 1);      \
    }                                                                      \
    if (PF) { STG_B(nb, b_u1 + 32, kn); STG_B(nb, b_u1 + 160, kn); }       \
    BAR();                                                                 \
    WAIT_LGKM0();                                                          \
    __builtin_amdgcn_s_setprio(1);                                         \
    MFMA_Q(4, 2, bf1);                                                     \
    __builtin_amdgcn_s_setprio(0);                                         \
    __builtin_amdgcn_sched_barrier(0);                                     \
    BAR();                                                                 \
    /* ---- ph3: (qm1,qn0); stage U2(next); gate for next ph0 ---- */      \
    if (PF) { STG_A(nb, 64 + a_u0, kn); STG_A(nb, 192 + a_u0, kn); }       \
    if (PF) { asm volatile("s_waitcnt vmcnt(4)" ::: "memory"); }           \
    BAR();                                                                 \
    __builtin_amdgcn_s_setprio(1);                                         \
    MFMA_Q(4, 0, bf0);                                                     \
    __builtin_amdgcn_s_setprio(0);                                         \
    __builtin_amdgcn_sched_barrier(0);                                     \
    BAR();                                                                 \
    cur = nb;                                                              \
  }

  for (int kt = 0; kt < NKT - 1; ++kt) {
    K_TILE(1, (kt + 1) * BK);
  }
  K_TILE(0, 0);

  // ---- epilogue ----
  const int hi = lane >> 4;
  const int col_l = lane & 15;
  float ssim = 0.f;
#pragma unroll
  for (int m = 0; m < 8; m++) {
    const int gibase = i0 + WR * 128 + m * 16 + hi * 4;
#pragma unroll
    for (int r = 0; r < 4; r++) {
      const int gi = gibase + r;
      float dsum = 0.f;
#pragma unroll
      for (int n = 0; n < 4; n++) {
        const int gj = j0 + WC * 64 + n * 16 + col_l;
        const float s = acc[m][n][r] * 2.0f;
        const float e = __expf(s);
        if (gj != gi) dsum += e;               // denom excludes diagonal
        if (gj < NROWS && gi < gj) ssim += s;  // triu(rows[:, :n], k=1)
      }
      dsum += __shfl_xor(dsum, 1);
      dsum += __shfl_xor(dsum, 2);
      dsum += __shfl_xor(dsum, 4);
      dsum += __shfl_xor(dsum, 8);
      if (col_l == 0) atomicAdd(&denom[gi], dsum);
    }
  }
#pragma unroll
  for (int msk = 1; msk < 64; msk <<= 1) ssim += __shfl_xor(ssim, msk);
  if (lane == 0 && j0 < NROWS) atomicAdd(sumsim, ssim);
}

__global__ __launch_bounds__(256) void finalize(const float* __restrict__ denom,
                                                const float* __restrict__ sumsim,
                                                float* __restrict__ out) {
  const int t = threadIdx.x;
  double s = 0.0;
  for (int i = t; i < NROWS; i += 256) {
    s += (double)(NROWS - 1 - i) * log((double)denom[i]);
  }
#pragma unroll
  for (int m = 1; m < 64; m <<= 1) s += __shfl_xor(s, m);
  __shared__ double ws_[4];
  if ((t & 63) == 0) ws_[t >> 6] = s;
  __syncthreads();
  if (t == 0) {
    const double loss = (ws_[0] + ws_[1] + ws_[2] + ws_[3]) - (double)sumsim[0];
    out[0] = (float)(-2.0 / (double)NROWS * (double)(NROWS - 1) * loss);
  }
}

extern "C" void kernel_launch(void* const* d_in, const int* in_sizes, int n_in,
                              void* d_out, int out_size, void* d_ws, size_t ws_size,
                              hipStream_t stream) {
  const float* emb = (const float*)d_in[0];
  unsigned short* zb = (unsigned short*)d_ws;
  float* denom = (float*)((char*)d_ws + (size_t)BROWS * BDIM * 2);
  float* sumsim = denom + NROWS;
  float* out = (float*)d_out;

  normalize_kernel<<<BROWS / 4, 256, 0, stream>>>(emb, zb, denom, sumsim);
  gemm_fused<<<(BROWS / BN) * (NROWS / BM), 512, 0, stream>>>(zb, denom, sumsim);
  finalize<<<1, 256, 0, stream>>>(denom, sumsim, out);
}

// Round 4
// 70.262 us; speedup vs baseline: 1.4223x; 1.0220x over previous
//
#include <hip/hip_runtime.h>
#include <stdint.h>

// ContrastiveLoss: B=8192, D=1024, n=2048, T=0.5
// K1: row-normalize f32 -> bf16 (one wave per row), zero denom/sumsim
// K2: 256x256-tile MFMA GEMM (BK=64, 8 waves), 4-phase pipeline with 2-tile-deep
//     prefetch (stage kt+2 into cur's dead regions), ONE vmcnt gate per K-tile,
//     XCD-chunked block mapping; epilogue: exp-row-sum + triu sum
// K3: scalar finalize (1024 threads)

#define BDIM 1024
#define BROWS 8192
#define NROWS 2048

#define BM 256
#define BN 256
#define BK 64
#define NKT (BDIM / BK)   // 16

typedef __attribute__((ext_vector_type(8))) short bf16x8;
typedef __attribute__((ext_vector_type(4))) float f32x4;

static __device__ __forceinline__ unsigned short f2bf(float x) {
  union { float f; unsigned int u; } a; a.f = x;
  unsigned int u = a.u;
  return (unsigned short)((u + 0x7fffu + ((u >> 16) & 1u)) >> 16);  // RNE
}

static __device__ __forceinline__ void gload_lds16(const unsigned short* g, unsigned short* l) {
  __builtin_amdgcn_global_load_lds(
      (const __attribute__((address_space(1))) uint32_t*)(const void*)g,
      (__attribute__((address_space(3))) uint32_t*)(void*)l,
      16, 0, 0);
}

__global__ __launch_bounds__(256) void normalize_kernel(const float* __restrict__ emb,
                                                        unsigned short* __restrict__ zb,
                                                        float* __restrict__ denom,
                                                        float* __restrict__ sumsim) {
  const int w = threadIdx.x >> 6;
  const int lane = threadIdx.x & 63;
  const int row = blockIdx.x * 4 + w;
  const float4* src = reinterpret_cast<const float4*>(emb + (size_t)row * BDIM);
  float4 v[4];
  float ss = 0.f;
#pragma unroll
  for (int i = 0; i < 4; i++) {
    v[i] = src[lane + i * 64];
    ss += v[i].x * v[i].x + v[i].y * v[i].y + v[i].z * v[i].z + v[i].w * v[i].w;
  }
#pragma unroll
  for (int m = 1; m < 64; m <<= 1) ss += __shfl_xor(ss, m);
  const float inv = rsqrtf(ss);
  ushort4* dst = reinterpret_cast<ushort4*>(zb + (size_t)row * BDIM);
#pragma unroll
  for (int i = 0; i < 4; i++) {
    ushort4 o;
    o.x = f2bf(v[i].x * inv);
    o.y = f2bf(v[i].y * inv);
    o.z = f2bf(v[i].z * inv);
    o.w = f2bf(v[i].w * inv);
    dst[lane + i * 64] = o;
  }
  if (blockIdx.x < NROWS / 4 && lane == 0) denom[row] = 0.f;
  if (blockIdx.x == 0 && threadIdx.x == 0) sumsim[0] = 0.f;
}

// ---------------- GEMM ----------------
// LDS: 2 buffers x (A 256x64 + B 256x64) bf16 = 128 KB.
// Row = 64 bf16 = 128 B = 8x16B slots; stored slot s of row r at s ^ (r&7).
// Regions (per buffer): U0 = A rows {0-63,128-191}, U2 = A rows {64-127,192-255},
//   U1 = B rows {x*64+0..31}, U3 = B rows {x*64+32..63}.
// Phase schedule per K-tile kt (reads buf cur; stages tile kt+2 INTO cur's dead regions):
//   ph0: read aA(q0)[8] + bf0[4]; lgkm(8) hint; BAR; lgkm0; MFMA q(0,0); BAR
//   ph1: read bf1[4]; stage U0,U1(kt+2); BAR; lgkm0; MFMA q(0,2); BAR
//   ph2: read aA(q1)[8]; stage U3(kt+2); BAR; lgkm0; MFMA q(4,2); BAR
//   ph3: stage U2(kt+2); GATE vmcnt(8); BAR; MFMA q(4,0); BAR
// Single gate/tile: forces tile kt+1 landed, leaves kt+2's 8 loads in flight.

__global__ __launch_bounds__(512, 2) void gemm_fused(const unsigned short* __restrict__ zb,
                                                     float* __restrict__ denom,
                                                     float* __restrict__ sumsim) {
  __shared__ unsigned short As[2][BM * BK];
  __shared__ unsigned short Bs[2][BN * BK];

  // XCD-chunked mapping: xcd owns 4 j-blocks x all 8 i-blocks
  const int bx = blockIdx.x;           // 0..255
  const int xcd = bx & 7;
  const int idx = bx >> 3;             // 0..31
  const int jb = xcd * 4 + (idx & 3);  // 0..31
  const int ib = idx >> 2;             // 0..7
  const int i0 = ib * BM;              // [0,2048)
  const int j0 = jb * BN;              // [0,8192)

  const int t = threadIdx.x;
  const int lane = t & 63;
  const int w = t >> 6;                // 0..7
  const int WR = w >> 2;               // 0..1
  const int WC = w & 3;                // 0..3

  // staging constants
  const int rsh = lane >> 3;                     // 0..7 row within 8-row group
  const int slsrc = (lane & 7) ^ rsh;            // logical slot fetched for stored pos lane&7
  const int a_u0 = w * 8;                        // A rows 0-63 base
  const int b_u1 = (w >> 2) * 64 + (w & 3) * 8;  // B qn=0 strip base

  // read constants
  const int q = lane >> 4;       // 0..3
  const int rsub = lane & 15;
  const int rx7 = rsub & 7;
  const int sA0 = q ^ rx7;       // stored slot for kk=0 (kk=1 -> ^4)
  const int arow = WR * 128 + rsub;
  const int brow = WC * 64 + rsub;

  f32x4 acc[8][4] = {};
  bf16x8 aA[4][2], bf0[2][2], bf1[2][2];

#define STG_A(buf, lr0, kk0) \
  gload_lds16(zb + (size_t)(i0 + (lr0) + rsh) * BDIM + (kk0) + slsrc * 8, &As[buf][(lr0) * BK])
#define STG_B(buf, lr0, kk0) \
  gload_lds16(zb + (size_t)(j0 + (lr0) + rsh) * BDIM + (kk0) + slsrc * 8, &Bs[buf][(lr0) * BK])

#define LDA(buf, qm, mm, kk) \
  (*reinterpret_cast<const bf16x8*>(&As[buf][(size_t)(arow + (qm) * 64 + (mm) * 16) * BK + ((sA0 ^ ((kk)*4)) * 8)]))
#define LDB(buf, qn, nn, kk) \
  (*reinterpret_cast<const bf16x8*>(&Bs[buf][(size_t)(brow + (qn) * 32 + (nn) * 16) * BK + ((sA0 ^ ((kk)*4)) * 8)]))

#define MFMA_Q(MB, NB, BF)                                                                       \
  _Pragma("unroll") for (int mm = 0; mm < 4; mm++)                                               \
  _Pragma("unroll") for (int nn = 0; nn < 2; nn++) {                                             \
    acc[(MB) + mm][(NB) + nn] =                                                                  \
        __builtin_amdgcn_mfma_f32_16x16x32_bf16(aA[mm][0], BF[nn][0], acc[(MB) + mm][(NB) + nn], 0, 0, 0); \
    acc[(MB) + mm][(NB) + nn] =                                                                  \
        __builtin_amdgcn_mfma_f32_16x16x32_bf16(aA[mm][1], BF[nn][1], acc[(MB) + mm][(NB) + nn], 0, 0, 0); \
  }

#define BAR() __builtin_amdgcn_s_barrier()
#define WAIT_LGKM0()                                        \
  asm volatile("s_waitcnt lgkmcnt(0)" ::: "memory");        \
  __builtin_amdgcn_sched_barrier(0)

#define STAGE_TILE(buf, kk0)                                  \
  {                                                           \
    STG_A(buf, a_u0, kk0);      STG_A(buf, 128 + a_u0, kk0);  \
    STG_B(buf, b_u1, kk0);      STG_B(buf, b_u1 + 128, kk0);  \
    STG_B(buf, b_u1 + 32, kk0); STG_B(buf, b_u1 + 160, kk0);  \
    STG_A(buf, 64 + a_u0, kk0); STG_A(buf, 192 + a_u0, kk0);  \
  }

  // ---- prologue: stage tiles 0 and 1 ----
  STAGE_TILE(0, 0);
  STAGE_TILE(1, BK);
  asm volatile("s_waitcnt vmcnt(8)" ::: "memory");  // tile0 landed; tile1 in flight
  BAR();

  int cur = 0;

#define GATE8 asm volatile("s_waitcnt vmcnt(8)" ::: "memory");
#define GATE0 asm volatile("s_waitcnt vmcnt(0)" ::: "memory");
#define GATEN

#define K_TILE(PF, kn, GATE)                                               \
  {                                                                        \
    /* ph0 */                                                              \
    _Pragma("unroll") for (int mm = 0; mm < 4; mm++) {                     \
      aA[mm][0] = LDA(cur, 0, mm, 0); aA[mm][1] = LDA(cur, 0, mm, 1);      \
    }                                                                      \
    _Pragma("unroll") for (int nn = 0; nn < 2; nn++) {                     \
      bf0[nn][0] = LDB(cur, 0, nn, 0); bf0[nn][1] = LDB(cur, 0, nn, 1);    \
    }                                                                      \
    asm volatile("s_waitcnt lgkmcnt(8)" ::: "memory");                     \
    BAR();                                                                 \
    WAIT_LGKM0();                                                          \
    __builtin_amdgcn_s_setprio(1);                                         \
    MFMA_Q(0, 0, bf0);                                                     \
    __builtin_amdgcn_s_setprio(0);                                         \
    BAR();                                                                 \
    /* ph1: U0/U1 of cur now dead -> stage kt+2 there */                   \
    _Pragma("unroll") for (int nn = 0; nn < 2; nn++) {                     \
      bf1[nn][0] = LDB(cur, 1, nn, 0); bf1[nn][1] = LDB(cur, 1, nn, 1);    \
    }                                                                      \
    if (PF) {                                                              \
      STG_A(cur, a_u0, kn); STG_A(cur, 128 + a_u0, kn);                    \
      STG_B(cur, b_u1, kn); STG_B(cur, b_u1 + 128, kn);                    \
    }                                                                      \
    BAR();                                                                 \
    WAIT_LGKM0();                                                          \
    __builtin_amdgcn_s_setprio(1);                                         \
    MFMA_Q(0, 2, bf1);                                                     \
    __builtin_amdgcn_s_setprio(0);                                         \
    BAR();                                                                 \
    /* ph2: U3 of cur dead -> stage */                                     \
    _Pragma("unroll") for (int mm = 0; mm < 4; mm++) {                     \
      aA[mm][0] = LDA(cur, 1, mm, 0); aA[mm][1] = LDA(cur, 1, mm, 1);      \
    }                                                                      \
    if (PF) { STG_B(cur, b_u1 + 32, kn); STG_B(cur, b_u1 + 160, kn); }     \
    BAR();                                                                 \
    WAIT_LGKM0();                                                          \
    __builtin_amdgcn_s_setprio(1);                                         \
    MFMA_Q(4, 2, bf1);                                                     \
    __builtin_amdgcn_s_setprio(0);                                         \
    BAR();                                                                 \
    /* ph3: U2 of cur dead -> stage; single gate per tile */               \
    if (PF) { STG_A(cur, 64 + a_u0, kn); STG_A(cur, 192 + a_u0, kn); }     \
    GATE                                                                   \
    BAR();                                                                 \
    __builtin_amdgcn_s_setprio(1);                                         \
    MFMA_Q(4, 0, bf0);                                                     \
    __builtin_amdgcn_s_setprio(0);                                         \
    BAR();                                                                 \
    cur ^= 1;                                                              \
  }

  for (int kt = 0; kt < NKT - 2; ++kt) {
    K_TILE(1, (size_t)(kt + 2) * BK, GATE8);
  }
  K_TILE(0, 0, GATE0);   // kt = 14: force tile15 landed
  K_TILE(0, 0, GATEN);   // kt = 15: last tile

  // ---- epilogue ----
  const int hi = lane >> 4;
  const int col_l = lane & 15;
  float ssim = 0.f;
#pragma unroll
  for (int m = 0; m < 8; m++) {
    const int gibase = i0 + WR * 128 + m * 16 + hi * 4;
#pragma unroll
    for (int r = 0; r < 4; r++) {
      const int gi = gibase + r;
      float dsum = 0.f;
#pragma unroll
      for (int n = 0; n < 4; n++) {
        const int gj = j0 + WC * 64 + n * 16 + col_l;
        const float s = acc[m][n][r] * 2.0f;
        const float e = __expf(s);
        if (gj != gi) dsum += e;               // denom excludes diagonal
        if (gj < NROWS && gi < gj) ssim += s;  // triu(rows[:, :n], k=1)
      }
      dsum += __shfl_xor(dsum, 1);
      dsum += __shfl_xor(dsum, 2);
      dsum += __shfl_xor(dsum, 4);
      dsum += __shfl_xor(dsum, 8);
      if (col_l == 0) atomicAdd(&denom[gi], dsum);
    }
  }
#pragma unroll
  for (int msk = 1; msk < 64; msk <<= 1) ssim += __shfl_xor(ssim, msk);
  if (lane == 0 && j0 < NROWS) atomicAdd(sumsim, ssim);
}

__global__ __launch_bounds__(1024) void finalize(const float* __restrict__ denom,
                                                 const float* __restrict__ sumsim,
                                                 float* __restrict__ out) {
  const int t = threadIdx.x;
  double s = 0.0;
#pragma unroll
  for (int i = t; i < NROWS; i += 1024) {
    s += (double)(NROWS - 1 - i) * log((double)denom[i]);
  }
#pragma unroll
  for (int m = 1; m < 64; m <<= 1) s += __shfl_xor(s, m);
  __shared__ double ws_[16];
  if ((t & 63) == 0) ws_[t >> 6] = s;
  __syncthreads();
  if (t == 0) {
    double tot = 0.0;
#pragma unroll
    for (int i = 0; i < 16; i++) tot += ws_[i];
    const double loss = tot - (double)sumsim[0];
    out[0] = (float)(-2.0 / (double)NROWS * (double)(NROWS - 1) * loss);
  }
}

extern "C" void kernel_launch(void* const* d_in, const int* in_sizes, int n_in,
                              void* d_out, int out_size, void* d_ws, size_t ws_size,
                              hipStream_t stream) {
  const float* emb = (const float*)d_in[0];
  unsigned short* zb = (unsigned short*)d_ws;
  float* denom = (float*)((char*)d_ws + (size_t)BROWS * BDIM * 2);
  float* sumsim = denom + NROWS;
  float* out = (float*)d_out;

  normalize_kernel<<<BROWS / 4, 256, 0, stream>>>(emb, zb, denom, sumsim);
  gemm_fused<<<(BROWS / BN) * (NROWS / BM), 512, 0, stream>>>(zb, denom, sumsim);
  finalize<<<1, 1024, 0, stream>>>(denom, sumsim, out);
}

// Round 5
// 69.697 us; speedup vs baseline: 1.4338x; 1.0081x over previous
//
#include <hip/hip_runtime.h>
#include <stdint.h>

// ContrastiveLoss: B=8192, D=1024, n=2048, T=0.5
// K1: row-normalize f32 -> bf16 (one wave per row), zero denom/sumsim
// K2: 256x256-tile MFMA GEMM (BK=64, 8 waves), RELAXED schedule:
//     one __syncthreads per K-tile, reads cur / stages nb (disjoint),
//     compiler-scheduled ds_read<->MFMA interleave, setprio on MFMA clusters.
// K3: scalar finalize (1024 threads)

#define BDIM 1024
#define BROWS 8192
#define NROWS 2048

#define BM 256
#define BN 256
#define BK 64
#define NKT (BDIM / BK)   // 16

typedef __attribute__((ext_vector_type(8))) short bf16x8;
typedef __attribute__((ext_vector_type(4))) float f32x4;

static __device__ __forceinline__ unsigned short f2bf(float x) {
  union { float f; unsigned int u; } a; a.f = x;
  unsigned int u = a.u;
  return (unsigned short)((u + 0x7fffu + ((u >> 16) & 1u)) >> 16);  // RNE
}

static __device__ __forceinline__ void gload_lds16(const unsigned short* g, unsigned short* l) {
  __builtin_amdgcn_global_load_lds(
      (const __attribute__((address_space(1))) uint32_t*)(const void*)g,
      (__attribute__((address_space(3))) uint32_t*)(void*)l,
      16, 0, 0);
}

__global__ __launch_bounds__(256) void normalize_kernel(const float* __restrict__ emb,
                                                        unsigned short* __restrict__ zb,
                                                        float* __restrict__ denom,
                                                        float* __restrict__ sumsim) {
  const int w = threadIdx.x >> 6;
  const int lane = threadIdx.x & 63;
  const int row = blockIdx.x * 4 + w;
  const float4* src = reinterpret_cast<const float4*>(emb + (size_t)row * BDIM);
  float4 v[4];
  float ss = 0.f;
#pragma unroll
  for (int i = 0; i < 4; i++) {
    v[i] = src[lane + i * 64];
    ss += v[i].x * v[i].x + v[i].y * v[i].y + v[i].z * v[i].z + v[i].w * v[i].w;
  }
#pragma unroll
  for (int m = 1; m < 64; m <<= 1) ss += __shfl_xor(ss, m);
  const float inv = rsqrtf(ss);
  ushort4* dst = reinterpret_cast<ushort4*>(zb + (size_t)row * BDIM);
#pragma unroll
  for (int i = 0; i < 4; i++) {
    ushort4 o;
    o.x = f2bf(v[i].x * inv);
    o.y = f2bf(v[i].y * inv);
    o.z = f2bf(v[i].z * inv);
    o.w = f2bf(v[i].w * inv);
    dst[lane + i * 64] = o;
  }
  if (blockIdx.x < NROWS / 4 && lane == 0) denom[row] = 0.f;
  if (blockIdx.x == 0 && threadIdx.x == 0) sumsim[0] = 0.f;
}

// ---------------- GEMM ----------------
// LDS: 2 buffers x (A 256x64 + B 256x64) bf16 = 128 KB.
// Row = 64 bf16 = 128 B = 8x16B slots; stored slot s of row r at s ^ (r&7)
// (applied via pre-swizzled global source; 2-way-free ds_read_b128).
// Per K-tile: reads come from buf cur, staging writes buf nb (strictly disjoint)
// -> single __syncthreads() per tile is the only sync. Its implicit vmcnt(0)
// drains loads issued one full tile earlier (stale, cheap). No manual waits:
// compiler emits fine-grained lgkmcnt for ds_read->MFMA.

__global__ __launch_bounds__(512, 2) void gemm_fused(const unsigned short* __restrict__ zb,
                                                     float* __restrict__ denom,
                                                     float* __restrict__ sumsim) {
  __shared__ unsigned short As[2][BM * BK];
  __shared__ unsigned short Bs[2][BN * BK];

  // XCD-chunked mapping: xcd owns 4 j-blocks x all 8 i-blocks
  const int bx = blockIdx.x;           // 0..255
  const int xcd = bx & 7;
  const int idx = bx >> 3;             // 0..31
  const int jb = xcd * 4 + (idx & 3);  // 0..31
  const int ib = idx >> 2;             // 0..7
  const int i0 = ib * BM;              // [0,2048)
  const int j0 = jb * BN;              // [0,8192)

  const int t = threadIdx.x;
  const int lane = t & 63;
  const int w = t >> 6;                // 0..7
  const int WR = w >> 2;               // 0..1
  const int WC = w & 3;                // 0..3

  // staging constants
  const int rsh = lane >> 3;                     // 0..7 row within 8-row group
  const int slsrc = (lane & 7) ^ rsh;            // fetched slot for stored pos lane&7
  const int a_u0 = w * 8;                        // A rows 0-63 base
  const int b_u1 = (w >> 2) * 64 + (w & 3) * 8;  // B qn=0 strip base

  // read constants
  const int q = lane >> 4;       // 0..3
  const int rsub = lane & 15;
  const int rx7 = rsub & 7;
  const int sA0 = q ^ rx7;       // stored slot for kk=0 (kk=1 -> ^4)
  const int arow = WR * 128 + rsub;
  const int brow = WC * 64 + rsub;

  f32x4 acc[8][4] = {};
  bf16x8 aA[4][2], bf0[2][2], bf1[2][2];

#define STG_A(buf, lr0, kk0) \
  gload_lds16(zb + (size_t)(i0 + (lr0) + rsh) * BDIM + (kk0) + slsrc * 8, &As[buf][(lr0) * BK])
#define STG_B(buf, lr0, kk0) \
  gload_lds16(zb + (size_t)(j0 + (lr0) + rsh) * BDIM + (kk0) + slsrc * 8, &Bs[buf][(lr0) * BK])

#define LDA(buf, qm, mm, kk) \
  (*reinterpret_cast<const bf16x8*>(&As[buf][(size_t)(arow + (qm) * 64 + (mm) * 16) * BK + ((sA0 ^ ((kk)*4)) * 8)]))
#define LDB(buf, qn, nn, kk) \
  (*reinterpret_cast<const bf16x8*>(&Bs[buf][(size_t)(brow + (qn) * 32 + (nn) * 16) * BK + ((sA0 ^ ((kk)*4)) * 8)]))

#define MFMA_Q(MB, NB, BF)                                                                       \
  _Pragma("unroll") for (int mm = 0; mm < 4; mm++)                                               \
  _Pragma("unroll") for (int nn = 0; nn < 2; nn++) {                                             \
    acc[(MB) + mm][(NB) + nn] =                                                                  \
        __builtin_amdgcn_mfma_f32_16x16x32_bf16(aA[mm][0], BF[nn][0], acc[(MB) + mm][(NB) + nn], 0, 0, 0); \
    acc[(MB) + mm][(NB) + nn] =                                                                  \
        __builtin_amdgcn_mfma_f32_16x16x32_bf16(aA[mm][1], BF[nn][1], acc[(MB) + mm][(NB) + nn], 0, 0, 0); \
  }

#define STAGE_TILE(buf, kk0)                                  \
  {                                                           \
    STG_A(buf, a_u0, kk0);      STG_A(buf, 128 + a_u0, kk0);  \
    STG_B(buf, b_u1, kk0);      STG_B(buf, b_u1 + 128, kk0);  \
    STG_B(buf, b_u1 + 32, kk0); STG_B(buf, b_u1 + 160, kk0);  \
    STG_A(buf, 64 + a_u0, kk0); STG_A(buf, 192 + a_u0, kk0);  \
  }

  // ---- prologue: stage tile 0 into buf 0; syncthreads drains vmcnt ----
  STAGE_TILE(0, 0);
  __syncthreads();

  int cur = 0;
  for (int kt = 0; kt < NKT; ++kt) {
    const int nb = cur ^ 1;
    const int pf = (kt + 1 < NKT);
    const int kn = (kt + 1) * BK;

    // stage half 1 of next tile (A first halves + B qn=0 strips)
    if (pf) {
      STG_A(nb, a_u0, kn);      STG_A(nb, 128 + a_u0, kn);
      STG_B(nb, b_u1, kn);      STG_B(nb, b_u1 + 128, kn);
    }

    // q0 fragment reads + B reads
#pragma unroll
    for (int mm = 0; mm < 4; mm++) {
      aA[mm][0] = LDA(cur, 0, mm, 0); aA[mm][1] = LDA(cur, 0, mm, 1);
    }
#pragma unroll
    for (int nn = 0; nn < 2; nn++) {
      bf0[nn][0] = LDB(cur, 0, nn, 0); bf0[nn][1] = LDB(cur, 0, nn, 1);
      bf1[nn][0] = LDB(cur, 1, nn, 0); bf1[nn][1] = LDB(cur, 1, nn, 1);
    }

    __builtin_amdgcn_s_setprio(1);
    MFMA_Q(0, 0, bf0);
    MFMA_Q(0, 2, bf1);
    __builtin_amdgcn_s_setprio(0);

    // stage half 2 of next tile
    if (pf) {
      STG_B(nb, b_u1 + 32, kn); STG_B(nb, b_u1 + 160, kn);
      STG_A(nb, 64 + a_u0, kn); STG_A(nb, 192 + a_u0, kn);
    }

    // q1 fragment reads
#pragma unroll
    for (int mm = 0; mm < 4; mm++) {
      aA[mm][0] = LDA(cur, 1, mm, 0); aA[mm][1] = LDA(cur, 1, mm, 1);
    }

    __builtin_amdgcn_s_setprio(1);
    MFMA_Q(4, 2, bf1);
    MFMA_Q(4, 0, bf0);
    __builtin_amdgcn_s_setprio(0);

    __syncthreads();  // tile boundary: drains stale staging + fences LDS
    cur = nb;
  }

  // ---- epilogue ----
  const int hi = lane >> 4;
  const int col_l = lane & 15;
  float ssim = 0.f;
#pragma unroll
  for (int m = 0; m < 8; m++) {
    const int gibase = i0 + WR * 128 + m * 16 + hi * 4;
#pragma unroll
    for (int r = 0; r < 4; r++) {
      const int gi = gibase + r;
      float dsum = 0.f;
#pragma unroll
      for (int n = 0; n < 4; n++) {
        const int gj = j0 + WC * 64 + n * 16 + col_l;
        const float s = acc[m][n][r] * 2.0f;
        const float e = __expf(s);
        if (gj != gi) dsum += e;               // denom excludes diagonal
        if (gj < NROWS && gi < gj) ssim += s;  // triu(rows[:, :n], k=1)
      }
      dsum += __shfl_xor(dsum, 1);
      dsum += __shfl_xor(dsum, 2);
      dsum += __shfl_xor(dsum, 4);
      dsum += __shfl_xor(dsum, 8);
      if (col_l == 0) atomicAdd(&denom[gi], dsum);
    }
  }
#pragma unroll
  for (int msk = 1; msk < 64; msk <<= 1) ssim += __shfl_xor(ssim, msk);
  if (lane == 0 && j0 < NROWS) atomicAdd(sumsim, ssim);
}

__global__ __launch_bounds__(1024) void finalize(const float* __restrict__ denom,
                                                 const float* __restrict__ sumsim,
                                                 float* __restrict__ out) {
  const int t = threadIdx.x;
  double s = 0.0;
#pragma unroll
  for (int i = t; i < NROWS; i += 1024) {
    s += (double)(NROWS - 1 - i) * log((double)denom[i]);
  }
#pragma unroll
  for (int m = 1; m < 64; m <<= 1) s += __shfl_xor(s, m);
  __shared__ double ws_[16];
  if ((t & 63) == 0) ws_[t >> 6] = s;
  __syncthreads();
  if (t == 0) {
    double tot = 0.0;
#pragma unroll
    for (int i = 0; i < 16; i++) tot += ws_[i];
    const double loss = tot - (double)sumsim[0];
    out[0] = (float)(-2.0 / (double)NROWS * (double)(NROWS - 1) * loss);
  }
}

extern "C" void kernel_launch(void* const* d_in, const int* in_sizes, int n_in,
                              void* d_out, int out_size, void* d_ws, size_t ws_size,
                              hipStream_t stream) {
  const float* emb = (const float*)d_in[0];
  unsigned short* zb = (unsigned short*)d_ws;
  float* denom = (float*)((char*)d_ws + (size_t)BROWS * BDIM * 2);
  float* sumsim = denom + NROWS;
  float* out = (float*)d_out;

  normalize_kernel<<<BROWS / 4, 256, 0, stream>>>(emb, zb, denom, sumsim);
  gemm_fused<<<(BROWS / BN) * (NROWS / BM), 512, 0, stream>>>(zb, denom, sumsim);
  finalize<<<1, 1024, 0, stream>>>(denom, sumsim, out);
}